// Round 3
// baseline (563.094 us; speedup 1.0000x reference)
//
#include <hip/hip_runtime.h>
#include <hip/hip_bf16.h>
#include <cstdint>

#define DI __device__ __forceinline__

typedef short bf16x8 __attribute__((ext_vector_type(8)));
typedef float f32x4 __attribute__((ext_vector_type(4)));
typedef unsigned short u16;
typedef unsigned short u16x4 __attribute__((ext_vector_type(4)));
typedef unsigned short u16x8 __attribute__((ext_vector_type(8)));

static constexpr int NV = 10, NE = 90, TT = 64;
static constexpr int R1 = 20480;   // 32*10*64 node rows
static constexpr int R2 = 184320;  // 32*90*64 edge rows

DI float bf2f(u16 u) { union { unsigned int i; float f; } x; x.i = ((unsigned int)u) << 16; return x.f; }
DI u16 f2bf(float f) { unsigned int u = __float_as_uint(f); return (u16)((u + 0x7FFF + ((u >> 16) & 1)) >> 16); }
DI float elu(float v) { return v > 0.f ? v : __expf(v) - 1.f; }

#define GLL(srcp, dstp) __builtin_amdgcn_global_load_lds( \
    (const __attribute__((address_space(1))) unsigned int*)(srcp), \
    (__attribute__((address_space(3))) unsigned int*)(dstp), 16, 0, 0)

// ---- combined weight transposes: [256,256] f32 -> [256,256] bf16 (n-major) --
__global__ __launch_bounds__(256) void transpose_all(
    const float* __restrict__ s0, u16* __restrict__ d0,
    const float* __restrict__ s1, u16* __restrict__ d1,
    const float* __restrict__ s2, u16* __restrict__ d2,
    const float* __restrict__ s3, u16* __restrict__ d3,
    const float* __restrict__ s4, u16* __restrict__ d4) {
    const float* s; u16* d;
    switch (blockIdx.y) {
        case 0: s = s0; d = d0; break;
        case 1: s = s1; d = d1; break;
        case 2: s = s2; d = d2; break;
        case 3: s = s3; d = d3; break;
        default: s = s4; d = d4; break;
    }
    int idx = blockIdx.x * 256 + threadIdx.x;
    int k = idx >> 8, n = idx & 255;
    d[(size_t)n * 256 + k] = f2bf(s[idx]);
}

__global__ void zero_stats(float* p, int n) {
    int i = blockIdx.x * 256 + threadIdx.x;
    if (i < n) p[i] = 0.f;
}

__global__ void conv_wo2(const float* __restrict__ src, u16* __restrict__ dst) {
    dst[threadIdx.x] = f2bf(src[threadIdx.x]);
}

// fold BN1 affine scale into w2a (transposed), shift into bias
__global__ __launch_bounds__(256) void fold_w2a(const float* __restrict__ w2a,
                                                const float* __restrict__ scsh1,
                                                u16* __restrict__ w2aT) {
    int k = blockIdx.x, n = threadIdx.x;
    w2aT[(size_t)n * 512 + k] = f2bf(scsh1[k & 255] * w2a[k * 256 + n]);
}
__global__ __launch_bounds__(256) void fold_b2a(const float* __restrict__ w2a,
                                                const float* __restrict__ scsh1,
                                                const float* __restrict__ b2a,
                                                float* __restrict__ b2aF) {
    int n = threadIdx.x;
    float s = b2a[n];
    for (int k = 0; k < 512; ++k) s += scsh1[256 + (k & 255)] * w2a[k * 256 + n];
    b2aF[n] = s;
}

__global__ void stats_final(const float* __restrict__ sums, const float* __restrict__ g,
                            const float* __restrict__ be, float invR, float* __restrict__ scsh) {
    int c = threadIdx.x;
    float mu = sums[c] * invR;
    float var = sums[256 + c] * invR - mu * mu;
    float rs = rsqrtf(var + 1e-5f);
    float sc = g[c] * rs;
    scsh[c] = sc;
    scsh[256 + c] = be[c] - mu * sc;
}

// -------------------- mlp1 fc1: K=4, VALU (round-1 verified) -----------------
__global__ __launch_bounds__(256) void mlp1_fc1(const float* __restrict__ x,
                                                const float* __restrict__ w1a,
                                                const float* __restrict__ b1a,
                                                u16* __restrict__ ha) {
    int tid = threadIdx.x;
    int row = blockIdx.x * 8 + (tid >> 5);
    int ch8 = (tid & 31) * 8;
    int b = row / (NV * TT);
    int v = (row >> 6) % NV;
    int t = row & 63;
    const float* xp = x + ((size_t)(b * TT + t) * NV + v) * 4;
    float x0 = xp[0], x1 = xp[1], x2 = xp[2], x3 = xp[3];
    u16x8 pack;
#pragma unroll
    for (int e = 0; e < 8; ++e) {
        int c = ch8 + e;
        float acc = b1a[c] + x0 * w1a[c] + x1 * w1a[256 + c] + x2 * w1a[512 + c] + x3 * w1a[768 + c];
        pack[e] = f2bf(elu(acc));
    }
    *(u16x8*)(ha + (size_t)row * 256 + ch8) = pack;
}

// ============================================================================
// 128x128 bf16 MFMA GEMM, BK=64, 4 waves, XOR-swizzled 128B LDS rows.
// LDS slot c of row r holds global k-chunk (c ^ (r&7)); swizzle applied on the
// GLOBAL source (global_load_lds writes linearly).  Reading chunk cl of row r
// hits slot (cl ^ (r&7)) -> banks spread 8 ways across 16 lanes (2-way, free).
// Operand swap: acc[i][j] = mfma(bv[j], av[i], .) -> lane holds
//   row m = m0+wm*64+i*16+(lane&15), cols n4..n4+3, n4 = n0+wn*64+j*16+(lane>>4)*4
// STG: 0 direct gload_lds | 1 node2edge gather gload_lds | 3 affine+relu regs
// ACT: 1 elu | 2 relu.  STATS: fused per-channel sum/sumsq atomics.
// ============================================================================
template <int STG, int ACT, bool STATS>
__global__ __launch_bounds__(256, 3) void mm(
    const u16* __restrict__ A, int K,
    const u16* __restrict__ Wt, const float* __restrict__ bias,
    const float* __restrict__ aux,
    u16* __restrict__ outB, float* __restrict__ stats)
{
    __shared__ u16 As[128 * 64];   // 16 KB
    __shared__ u16 Bs[128 * 64];   // 16 KB

    const int tid = threadIdx.x;
    const int wid = tid >> 6, lane = tid & 63;
    const int g = lane >> 4, lr = lane & 15;
    const int bm = blockIdx.x >> 1, bn = blockIdx.x & 1;
    const int m0 = bm * 128, n0 = bn * 128;
    const int wm = wid >> 1, wn = wid & 1;
    const int srow = tid >> 3;                              // 0..31
    const int cS8 = ((tid & 7) ^ (srow & 7)) * 8;           // swizzled src chunk

    size_t ab[4], sb[4], rb[4];
    if constexpr (STG == 1) {
#pragma unroll
        for (int q = 0; q < 4; ++q) {
            int m = m0 + q * 32 + srow;
            int t = m & 63, be = m >> 6, e = be % NE, b = be / NE;
            int s = e / 9, kk = e - s * 9, r = kk + (kk >= s ? 1 : 0);
            sb[q] = ((size_t)((b * NV + s) * TT + t)) * 256;
            rb[q] = ((size_t)((b * NV + r) * TT + t)) * 256;
        }
    } else if constexpr (STG == 0) {
#pragma unroll
        for (int q = 0; q < 4; ++q) ab[q] = (size_t)(m0 + q * 32 + srow) * K;
    }
    size_t bb[4];
#pragma unroll
    for (int q = 0; q < 4; ++q) bb[q] = (size_t)(n0 + q * 32 + srow) * K;

    f32x4 acc[4][4];
#pragma unroll
    for (int i = 0; i < 4; ++i)
#pragma unroll
        for (int j = 0; j < 4; ++j) acc[i][j] = (f32x4)0.f;

    for (int k0 = 0; k0 < K; k0 += 64) {
        // ---- stage A ----
        if constexpr (STG == 0) {
#pragma unroll
            for (int q = 0; q < 4; ++q)
                GLL(A + ab[q] + k0 + cS8, As + (q * 32 + wid * 8) * 64);
        } else if constexpr (STG == 1) {
#pragma unroll
            for (int q = 0; q < 4; ++q) {
                size_t base = (k0 < 256 ? sb[q] : rb[q]) + (k0 & 255);
                GLL(A + base + cS8, As + (q * 32 + wid * 8) * 64);
            }
        } else {  // STG == 3: affine(aux)+relu, register-staged
#pragma unroll
            for (int q = 0; q < 4; ++q) {
                int row = q * 32 + srow;
                u16x8 vin = *(const u16x8*)(A + (size_t)(m0 + row) * 256 + k0 + cS8);
                u16x8 pk;
#pragma unroll
                for (int e = 0; e < 8; ++e) {
                    int ch = k0 + cS8 + e;
                    float f = bf2f(vin[e]) * aux[ch] + aux[256 + ch];
                    pk[e] = f2bf(f > 0.f ? f : 0.f);
                }
                *(u16x8*)&As[row * 64 + (tid & 7) * 8] = pk;
            }
        }
        // ---- stage B (weights) ----
#pragma unroll
        for (int q = 0; q < 4; ++q)
            GLL(Wt + bb[q] + k0 + cS8, Bs + (q * 32 + wid * 8) * 64);
        __syncthreads();
        // ---- MFMA ----
#pragma unroll
        for (int s = 0; s < 2; ++s) {
            bf16x8 av[4], bv[4];
#pragma unroll
            for (int i = 0; i < 4; ++i) {
                int r = wm * 64 + i * 16 + lr;
                av[i] = *(const bf16x8*)&As[r * 64 + ((s * 4 + g) ^ (lr & 7)) * 8];
            }
#pragma unroll
            for (int j = 0; j < 4; ++j) {
                int r = wn * 64 + j * 16 + lr;
                bv[j] = *(const bf16x8*)&Bs[r * 64 + ((s * 4 + g) ^ (lr & 7)) * 8];
            }
#pragma unroll
            for (int i = 0; i < 4; ++i)
#pragma unroll
                for (int j = 0; j < 4; ++j)
                    acc[i][j] = __builtin_amdgcn_mfma_f32_16x16x32_bf16(bv[j], av[i], acc[i][j], 0, 0, 0);
        }
        __syncthreads();
    }

    // ---- epilogue: bias + act (+stats) + packed store ----
    float sv[4][4], qv[4][4];
    if constexpr (STATS) {
#pragma unroll
        for (int j = 0; j < 4; ++j)
#pragma unroll
            for (int r = 0; r < 4; ++r) { sv[j][r] = 0.f; qv[j][r] = 0.f; }
    }
#pragma unroll
    for (int j = 0; j < 4; ++j) {
        int n4 = n0 + wn * 64 + j * 16 + g * 4;
        f32x4 bq = *(const f32x4*)(bias + n4);
#pragma unroll
        for (int i = 0; i < 4; ++i) {
            int m = m0 + wm * 64 + i * 16 + lr;
            u16x4 pk;
#pragma unroll
            for (int r = 0; r < 4; ++r) {
                float v = acc[i][j][r] + bq[r];
                v = (ACT == 1) ? elu(v) : (v > 0.f ? v : 0.f);
                if constexpr (STATS) { sv[j][r] += v; qv[j][r] += v * v; }
                pk[r] = f2bf(v);
            }
            *(u16x4*)(outB + (size_t)m * 256 + n4) = pk;
        }
    }
    if constexpr (STATS) {
#pragma unroll
        for (int j = 0; j < 4; ++j)
#pragma unroll
            for (int r = 0; r < 4; ++r) {
                float s = sv[j][r], q_ = qv[j][r];
                s += __shfl_xor(s, 1);  q_ += __shfl_xor(q_, 1);
                s += __shfl_xor(s, 2);  q_ += __shfl_xor(q_, 2);
                s += __shfl_xor(s, 4);  q_ += __shfl_xor(q_, 4);
                s += __shfl_xor(s, 8);  q_ += __shfl_xor(q_, 8);
                if (lr == 0) {
                    int n = n0 + wn * 64 + j * 16 + g * 4 + r;
                    atomicAdd(&stats[n], s);
                    atomicAdd(&stats[256 + n], q_);
                }
            }
    }
}

// -------------------- edge2node: incidence sum + BN2 affine (verified) -------
__global__ __launch_bounds__(256) void edge2node(const u16* __restrict__ h2,
                                                 const float* __restrict__ scsh2,
                                                 u16* __restrict__ n1) {
    int tid = threadIdx.x;
    int row = blockIdx.x * 8 + (tid >> 5);
    int ch8 = (tid & 31) * 8;
    int t = row & 63;
    int bv = row >> 6;
    int v = bv % NV;
    int b = bv / NV;
    float acc[8] = {0, 0, 0, 0, 0, 0, 0, 0};
#pragma unroll
    for (int i = 0; i < 9; ++i) {
        int s = i + (i >= v ? 1 : 0);
        int e = s * 9 + (v < s ? v : v - 1);
        u16x8 vv = *(const u16x8*)(h2 + ((size_t)((b * NE + e) * TT + t)) * 256 + ch8);
#pragma unroll
        for (int k = 0; k < 8; ++k) acc[k] += bf2f(vv[k]);
    }
    const float inv9 = 1.f / 9.f;
    u16x8 o;
#pragma unroll
    for (int k = 0; k < 8; ++k) {
        int c = ch8 + k;
        o[k] = f2bf(scsh2[c] * (acc[k] * inv9) + scsh2[256 + c]);
    }
    *(u16x8*)(n1 + (size_t)row * 256 + ch8) = o;
}

// -------------------- final head: dot(a2_row, wo2) + bo2 (verified) ----------
__global__ __launch_bounds__(256) void head2(const u16* __restrict__ a2,
                                             const u16* __restrict__ wo2t,
                                             const float* __restrict__ bo2,
                                             float* __restrict__ out) {
    int tid = threadIdx.x;
    int row = blockIdx.x * 8 + (tid >> 5);
    int l32 = tid & 31;
    int ch8 = l32 * 8;
    u16x8 a = *(const u16x8*)(a2 + (size_t)row * 256 + ch8);
    u16x8 w = *(const u16x8*)(wo2t + ch8);
    float p = 0.f;
#pragma unroll
    for (int k = 0; k < 8; ++k) p += bf2f(a[k]) * bf2f(w[k]);
#pragma unroll
    for (int off = 16; off > 0; off >>= 1) p += __shfl_down(p, off, 32);
    if (l32 == 0) {
        int b = row / (NV * TT);
        int v = (row >> 6) % NV;
        int t = row & 63;
        out[(size_t)(b * TT + t) * NV + v] = p + bo2[0];
    }
}

extern "C" void kernel_launch(void* const* d_in, const int* in_sizes, int n_in,
                              void* d_out, int out_size, void* d_ws, size_t ws_size,
                              hipStream_t stream) {
    const float* x   = (const float*)d_in[0];
    const float* w1a = (const float*)d_in[1];
    const float* b1a = (const float*)d_in[2];
    const float* w1b = (const float*)d_in[3];
    const float* b1b = (const float*)d_in[4];
    const float* g1  = (const float*)d_in[5];
    const float* be1 = (const float*)d_in[6];
    const float* w2a = (const float*)d_in[7];
    const float* b2a = (const float*)d_in[8];
    const float* w2b = (const float*)d_in[9];
    const float* b2b = (const float*)d_in[10];
    const float* g2  = (const float*)d_in[11];
    const float* be2 = (const float*)d_in[12];
    const float* w3a = (const float*)d_in[13];
    const float* b3a = (const float*)d_in[14];
    const float* w3b = (const float*)d_in[15];
    const float* b3b = (const float*)d_in[16];
    const float* g3  = (const float*)d_in[17];
    const float* be3 = (const float*)d_in[18];
    const float* wo1 = (const float*)d_in[19];
    const float* bo1 = (const float*)d_in[20];
    const float* wo2 = (const float*)d_in[21];
    const float* bo2 = (const float*)d_in[22];
    float* out = (float*)d_out;

    char* ws = (char*)d_ws;
    size_t off = 0;
    auto alloc = [&](size_t bytes) {
        void* p = ws + off;
        off = (off + bytes + 255) & ~(size_t)255;
        return p;
    };
    u16* w1bT = (u16*)alloc(256 * 256 * 2);
    u16* w2aT = (u16*)alloc(256 * 512 * 2);
    u16* w2bT = (u16*)alloc(256 * 256 * 2);
    u16* w3aT = (u16*)alloc(256 * 256 * 2);
    u16* w3bT = (u16*)alloc(256 * 256 * 2);
    u16* wo1T = (u16*)alloc(256 * 256 * 2);
    u16* wo2T = (u16*)alloc(256 * 2);
    float* sums  = (float*)alloc(3 * 512 * 4);
    float* scsh1 = (float*)alloc(512 * 4);
    float* scsh2 = (float*)alloc(512 * 4);
    float* scsh3 = (float*)alloc(512 * 4);
    float* b2aF  = (float*)alloc(256 * 4);
    u16* S0 = (u16*)alloc((size_t)R1 * 256 * 2);
    u16* S1 = (u16*)alloc((size_t)R1 * 256 * 2);
    u16* S2 = (u16*)alloc((size_t)R1 * 256 * 2);
    u16* BIG1 = (u16*)alloc((size_t)R2 * 256 * 2);
    u16* BIG2 = (u16*)alloc((size_t)R2 * 256 * 2);

    dim3 tgrid(256, 5);
    transpose_all<<<tgrid, 256, 0, stream>>>(w1b, w1bT, w2b, w2bT, w3a, w3aT,
                                             w3b, w3bT, wo1, wo1T);
    zero_stats<<<6, 256, 0, stream>>>(sums, 3 * 512);
    conv_wo2<<<1, 256, 0, stream>>>(wo2, wo2T);

    // mlp1: fc1 (VALU) + fc2 GEMM with fused stats
    mlp1_fc1<<<R1 / 8, 256, 0, stream>>>(x, w1a, b1a, S0);
    mm<0, 1, true><<<(R1 / 128) * 2, 256, 0, stream>>>(S0, 256, w1bT, b1b, nullptr, S1, sums);
    stats_final<<<1, 256, 0, stream>>>(sums, g1, be1, 1.f / R1, scsh1);
    fold_w2a<<<512, 256, 0, stream>>>(w2a, scsh1, w2aT);
    fold_b2a<<<1, 256, 0, stream>>>(w2a, scsh1, b2a, b2aF);

    // mlp2: gather fc1 (BN1 folded into weights), fc2 with fused stats
    mm<1, 1, false><<<(R2 / 128) * 2, 256, 0, stream>>>(S1, 512, w2aT, b2aF, nullptr, BIG1, nullptr);
    mm<0, 1, true><<<(R2 / 128) * 2, 256, 0, stream>>>(BIG1, 256, w2bT, b2b, nullptr, BIG2, sums + 512);
    stats_final<<<1, 256, 0, stream>>>(sums + 512, g2, be2, 1.f / R2, scsh2);

    edge2node<<<R1 / 8, 256, 0, stream>>>(BIG2, scsh2, S0);

    // mlp3: two GEMMs, stats fused into fc2
    mm<0, 1, false><<<(R1 / 128) * 2, 256, 0, stream>>>(S0, 256, w3aT, b3a, nullptr, S1, nullptr);
    mm<0, 1, true><<<(R1 / 128) * 2, 256, 0, stream>>>(S1, 256, w3bT, b3b, nullptr, S2, sums + 1024);
    stats_final<<<1, 256, 0, stream>>>(sums + 1024, g3, be3, 1.f / R1, scsh3);

    // head: affine3+relu staged into wo1 GEMM, relu stored; then dot wo2
    mm<3, 2, false><<<(R1 / 128) * 2, 256, 0, stream>>>(S2, 256, wo1T, bo1, scsh3, S1, nullptr);
    head2<<<R1 / 8, 256, 0, stream>>>(S1, wo2T, bo2, out);
}